// Round 5
// baseline (233.578 us; speedup 1.0000x reference)
//
#include <hip/hip_runtime.h>
#include <hip/hip_bf16.h>
#include <stdint.h>

#define D 128

using bf16x8 = __attribute__((ext_vector_type(8))) short;
using f32x4  = __attribute__((ext_vector_type(4))) float;

__device__ __forceinline__ unsigned short f2bf(float f) {
    unsigned u = __float_as_uint(f);
    u = (u + 0x7fffu + ((u >> 16) & 1u)) >> 16;   // RNE
    return (unsigned short)u;
}
__device__ __forceinline__ float bf2f(unsigned short h) {
    return __uint_as_float(((unsigned)h) << 16);
}

// 8 fp32 -> 8 bf16 via packed HW cvt (RNE)
__device__ __forceinline__ bf16x8 cvt8(float4 a, float4 b) {
    union { bf16x8 v; __hip_bfloat162 h[4]; } u;
    u.h[0] = __float22bfloat162_rn(make_float2(a.x, a.y));
    u.h[1] = __float22bfloat162_rn(make_float2(a.z, a.w));
    u.h[2] = __float22bfloat162_rn(make_float2(b.x, b.y));
    u.h[3] = __float22bfloat162_rn(make_float2(b.z, b.w));
    return u.v;
}

// ---------- prep: feat->bf16 cast  +  Wt[r][c][k]=bf16(W[r][k][c])  +  degree count ----------
__global__ __launch_bounds__(256) void prep_kernel(
    const float* __restrict__ feat, unsigned short* __restrict__ featb,
    const float* __restrict__ W, unsigned short* __restrict__ Wt,
    const int* __restrict__ dst, int* __restrict__ deg, int* __restrict__ ord,
    int fcTotal /*chunks of 8*/, int wtTotal, int E)
{
    int fcBlocks = (fcTotal + 255) >> 8;
    int wtBlocks = (wtTotal + 255) >> 8;
    int b = blockIdx.x;
    if (b < fcBlocks) {
        int i = b * 256 + threadIdx.x;
        if (i < fcTotal && featb) {
            const float4* p = (const float4*)feat + (size_t)i * 2;
            float4 a = p[0], c = p[1];
            *(bf16x8*)(featb + (size_t)i * 8) = cvt8(a, c);
        }
    } else if (b < fcBlocks + wtBlocks) {
        int idx = (b - fcBlocks) * 256 + threadIdx.x;
        if (idx < wtTotal) {
            int r = idx >> 14;            // /(D*D)
            int rem = idx & 16383;
            int k = rem >> 7, c = rem & 127;
            Wt[(r << 14) + (c << 7) + k] = f2bf(W[idx]);
        }
    } else {
        int e = (b - fcBlocks - wtBlocks) * 256 + threadIdx.x;
        if (e < E) ord[e] = atomicAdd(&deg[dst[e]], 1);
    }
}

// ---------- Phase 1: H[r][n][c] = bf16( feat[n][:] @ W[r] ) ----------
// Max-concurrency design: NO LDS, NO barriers. Wave = 32 nodes x 1 rel.
// B-frags (feat, bf16) = 32 VGPRs loaded once; A-frags (Wt) streamed from
// L2-resident Wt (256 KB total) per ct. grid = (N/128, R) -> 3128 blocks,
// ~12 waves/SIMD queued; latency hidden by wave count + 8 independent ct chains.
__global__ __launch_bounds__(256) void transform6_kernel(
    const unsigned short* __restrict__ featb, const unsigned short* __restrict__ Wt,
    unsigned short* __restrict__ H, int N)
{
    const int rel  = blockIdx.y;
    const int tid  = threadIdx.x;
    const int wave = tid >> 6, lane = tid & 63;
    const int q    = lane >> 4, mlo = lane & 15;

    const int nb = blockIdx.x * 128 + wave * 32;   // wave's 32 nodes

    // B-frags: B[k = ks*32+q*8+j][n = mlo], node = nb + g*16 + mlo
    bf16x8 bfr[2][4];
    #pragma unroll
    for (int g = 0; g < 2; ++g) {
        int node = nb + g * 16 + mlo;
        int ld = node < N ? node : N - 1;
        const unsigned short* fp = featb + (size_t)ld * D + q * 8;
        #pragma unroll
        for (int ks = 0; ks < 4; ++ks)
            bfr[g][ks] = *(const bf16x8*)(fp + ks * 32);
    }

    const unsigned short* wb = Wt + ((size_t)rel << 14) + (size_t)mlo * D + q * 8;
    const size_t Hb = (size_t)rel * N * D;
    const int n0 = nb + mlo, n1 = nb + 16 + mlo;
    unsigned short* h0 = H + Hb + (size_t)n0 * D + q * 4;
    unsigned short* h1 = H + Hb + (size_t)n1 * D + q * 4;

    #pragma unroll
    for (int ct = 0; ct < 8; ++ct) {
        // A-frags: A[m = ct*16+mlo][k = ks*32+q*8+j], from L2-hot Wt
        bf16x8 af[4];
        #pragma unroll
        for (int ks = 0; ks < 4; ++ks)
            af[ks] = *(const bf16x8*)(wb + ct * (16 * D) + ks * 32);
        f32x4 a0 = {0.f, 0.f, 0.f, 0.f}, a1 = {0.f, 0.f, 0.f, 0.f};
        #pragma unroll
        for (int ks = 0; ks < 4; ++ks) {
            a0 = __builtin_amdgcn_mfma_f32_16x16x32_bf16(af[ks], bfr[0][ks], a0, 0, 0, 0);
            a1 = __builtin_amdgcn_mfma_f32_16x16x32_bf16(af[ks], bfr[1][ks], a1, 0, 0, 0);
        }
        // D[m=channel][n=node]: col=mlo (node), row=q*4+rr (channel)
        if (n0 < N) {
            union { ushort4 s; __hip_bfloat162 h[2]; } o;
            o.h[0] = __float22bfloat162_rn(make_float2(a0[0], a0[1]));
            o.h[1] = __float22bfloat162_rn(make_float2(a0[2], a0[3]));
            *(ushort4*)(h0 + ct * 16) = o.s;
        }
        if (n1 < N) {
            union { ushort4 s; __hip_bfloat162 h[2]; } o;
            o.h[0] = __float22bfloat162_rn(make_float2(a1[0], a1[1]));
            o.h[1] = __float22bfloat162_rn(make_float2(a1[2], a1[3]));
            *(ushort4*)(h1 + ct * 16) = o.s;
        }
    }
}

// fp32-feat variant (used only when workspace can't hold featb)
__global__ __launch_bounds__(256) void transform6f_kernel(
    const float* __restrict__ feat, const unsigned short* __restrict__ Wt,
    unsigned short* __restrict__ H, int N)
{
    const int rel  = blockIdx.y;
    const int tid  = threadIdx.x;
    const int wave = tid >> 6, lane = tid & 63;
    const int q    = lane >> 4, mlo = lane & 15;

    const int nb = blockIdx.x * 128 + wave * 32;

    bf16x8 bfr[2][4];
    #pragma unroll
    for (int g = 0; g < 2; ++g) {
        int node = nb + g * 16 + mlo;
        int ld = node < N ? node : N - 1;
        const float* fp = feat + (size_t)ld * D + q * 8;
        #pragma unroll
        for (int ks = 0; ks < 4; ++ks)
            bfr[g][ks] = cvt8(*(const float4*)(fp + ks * 32), *(const float4*)(fp + ks * 32 + 4));
    }

    const unsigned short* wb = Wt + ((size_t)rel << 14) + (size_t)mlo * D + q * 8;
    const size_t Hb = (size_t)rel * N * D;
    const int n0 = nb + mlo, n1 = nb + 16 + mlo;
    unsigned short* h0 = H + Hb + (size_t)n0 * D + q * 4;
    unsigned short* h1 = H + Hb + (size_t)n1 * D + q * 4;

    #pragma unroll
    for (int ct = 0; ct < 8; ++ct) {
        bf16x8 af[4];
        #pragma unroll
        for (int ks = 0; ks < 4; ++ks)
            af[ks] = *(const bf16x8*)(wb + ct * (16 * D) + ks * 32);
        f32x4 a0 = {0.f, 0.f, 0.f, 0.f}, a1 = {0.f, 0.f, 0.f, 0.f};
        #pragma unroll
        for (int ks = 0; ks < 4; ++ks) {
            a0 = __builtin_amdgcn_mfma_f32_16x16x32_bf16(af[ks], bfr[0][ks], a0, 0, 0, 0);
            a1 = __builtin_amdgcn_mfma_f32_16x16x32_bf16(af[ks], bfr[1][ks], a1, 0, 0, 0);
        }
        if (n0 < N) {
            union { ushort4 s; __hip_bfloat162 h[2]; } o;
            o.h[0] = __float22bfloat162_rn(make_float2(a0[0], a0[1]));
            o.h[1] = __float22bfloat162_rn(make_float2(a0[2], a0[3]));
            *(ushort4*)(h0 + ct * 16) = o.s;
        }
        if (n1 < N) {
            union { ushort4 s; __hip_bfloat162 h[2]; } o;
            o.h[0] = __float22bfloat162_rn(make_float2(a1[0], a1[1]));
            o.h[1] = __float22bfloat162_rn(make_float2(a1[2], a1[3]));
            *(ushort4*)(h1 + ct * 16) = o.s;
        }
    }
}

// ---------- CSR scan kernels ----------
__global__ __launch_bounds__(256) void k_blocksum(
    const int* __restrict__ deg, int* __restrict__ part, int N)
{
    int t = threadIdx.x, i = blockIdx.x * 256 + t;
    int v = (i < N) ? deg[i] : 0;
    #pragma unroll
    for (int o = 32; o > 0; o >>= 1) v += __shfl_down(v, o, 64);
    __shared__ int ws_[4];
    if ((t & 63) == 0) ws_[t >> 6] = v;
    __syncthreads();
    if (t == 0) part[blockIdx.x] = ws_[0] + ws_[1] + ws_[2] + ws_[3];
}

__global__ __launch_bounds__(256) void k_scanpart(int* part, int nb)
{
    __shared__ int s[256];
    int t = threadIdx.x;
    int v = (t < nb) ? part[t] : 0;
    s[t] = v;
    #pragma unroll
    for (int o = 1; o < 256; o <<= 1) {
        __syncthreads();
        int x = (t >= o) ? s[t - o] : 0;
        __syncthreads();
        s[t] += x;
    }
    if (t < nb) part[t] = s[t] - v;
}

__global__ __launch_bounds__(256) void k_scanfinal(
    const int* __restrict__ deg, const int* __restrict__ part,
    int* __restrict__ off, int N, int E)
{
    __shared__ int s[256];
    int t = threadIdx.x, i = blockIdx.x * 256 + t;
    int v = (i < N) ? deg[i] : 0;
    s[t] = v;
    #pragma unroll
    for (int o = 1; o < 256; o <<= 1) {
        __syncthreads();
        int x = (t >= o) ? s[t - o] : 0;
        __syncthreads();
        s[t] += x;
    }
    if (i < N) off[i] = part[blockIdx.x] + s[t] - v;
    if (i == 0) off[N] = E;
}

__global__ __launch_bounds__(256) void k_fill(
    const int* __restrict__ dst, const int* __restrict__ et,
    const int* __restrict__ src, const int* __restrict__ off,
    const int* __restrict__ ord, unsigned int* __restrict__ sorted, int E)
{
    int e = blockIdx.x * 256 + threadIdx.x;
    if (e >= E) return;
    sorted[off[dst[e]] + ord[e]] = ((unsigned)et[e] << 16) | (unsigned)src[e];
}

// ---------- Phase 2: per-node gather; 8-deep load pipeline ----------
__global__ __launch_bounds__(256) void k_gather2(
    const unsigned short* __restrict__ H, const unsigned int* __restrict__ sorted,
    const int* __restrict__ off, const float* __restrict__ feat,
    float* __restrict__ out, int N)
{
    int n = blockIdx.x * 4 + (threadIdx.x >> 6);
    if (n >= N) return;
    int lane = threadIdx.x & 63;

    float2 acc = ((const float2*)feat)[(size_t)n * 64 + lane];   // (1+eps)*h

    int j0 = __builtin_amdgcn_readfirstlane(off[n]);
    int j1 = __builtin_amdgcn_readfirstlane(off[n + 1]);
    int deg = j1 - j0;
    if (deg > 0) {
        unsigned ep = sorted[j0 + (lane < deg ? lane : deg - 1)];
        int m = deg < 64 ? deg : 64;
        int i = 0;
        for (; i + 8 <= m; i += 8) {
            unsigned a[8];
            #pragma unroll
            for (int u = 0; u < 8; ++u) {
                unsigned p = __shfl(ep, i + u);
                a[u] = *(const unsigned*)(H + (((size_t)(p >> 16) * N + (p & 0xffffu)) << 7) + lane * 2);
            }
            #pragma unroll
            for (int u = 0; u < 8; ++u) {
                acc.x += bf2f((unsigned short)(a[u] & 0xffffu));
                acc.y += bf2f((unsigned short)(a[u] >> 16));
            }
        }
        for (; i < m; ++i) {
            unsigned p = __shfl(ep, i);
            unsigned a0 = *(const unsigned*)(H + (((size_t)(p >> 16) * N + (p & 0xffffu)) << 7) + lane * 2);
            acc.x += bf2f((unsigned short)(a0 & 0xffffu));
            acc.y += bf2f((unsigned short)(a0 >> 16));
        }
        for (int j = j0 + 64; j < j1; ++j) {   // rare high-degree tail
            unsigned p = sorted[j];
            unsigned a0 = *(const unsigned*)(H + (((size_t)(p >> 16) * N + (p & 0xffffu)) << 7) + lane * 2);
            acc.x += bf2f((unsigned short)(a0 & 0xffffu));
            acc.y += bf2f((unsigned short)(a0 >> 16));
        }
    }
    ((float2*)out)[(size_t)n * 64 + lane] = acc;
}

// ---------- fallbacks ----------
__global__ __launch_bounds__(256) void init_kernel(
    const float* __restrict__ feat, float* __restrict__ out, int n4)
{
    int i = blockIdx.x * 256 + threadIdx.x;
    if (i < n4) ((float4*)out)[i] = ((const float4*)feat)[i];
}

__global__ __launch_bounds__(128) void edge_matvec_kernel(
    const float* __restrict__ feat, const float* __restrict__ W,
    const int* __restrict__ et, const int* __restrict__ src,
    const int* __restrict__ dst, float* __restrict__ out, int E)
{
    __shared__ float xs[D];
    int e = blockIdx.x;
    int c = threadIdx.x;
    int s = src[e], r = et[e], d = dst[e];
    xs[c] = feat[(size_t)s * D + c];
    __syncthreads();
    const float* Wr = W + (size_t)r * D * D;
    float acc = 0.f;
    #pragma unroll 8
    for (int k = 0; k < D; ++k) acc += xs[k] * Wr[(size_t)k * D + c];
    atomicAdd(out + (size_t)d * D + c, acc);
}

static inline size_t al256(size_t x) { return (x + 255) & ~(size_t)255; }

extern "C" void kernel_launch(void* const* d_in, const int* in_sizes, int n_in,
                              void* d_out, int out_size, void* d_ws, size_t ws_size,
                              hipStream_t stream) {
    const float* feat = (const float*)d_in[0];
    const float* W    = (const float*)d_in[1];
    const int*   et   = (const int*)d_in[2];
    const int*   src  = (const int*)d_in[3];
    const int*   dst  = (const int*)d_in[4];
    float* out = (float*)d_out;

    const int N = in_sizes[0] / D;
    const int R = in_sizes[1] / (D * D);
    const int E = in_sizes[2];

    // Workspace layout; featb LAST so we degrade gracefully if ws is tight
    size_t hB   = al256((size_t)R * N * D * sizeof(unsigned short));
    size_t wtB  = al256((size_t)R * D * D * sizeof(unsigned short));
    size_t offB = al256((size_t)(N + 1) * sizeof(int));
    size_t degB = al256((size_t)N * sizeof(int));
    size_t ordB = al256((size_t)E * sizeof(int));
    size_t parB = al256(1024 * sizeof(int));
    size_t srtB = al256((size_t)E * sizeof(unsigned int));
    size_t fbB  = al256((size_t)N * D * sizeof(unsigned short));
    size_t need_base = hB + wtB + offB + degB + ordB + parB + srtB;
    size_t need_full = need_base + fbB;

    const int nbScan = (N + 255) / 256;
    const bool packable = (N <= 65536) && (R <= 65536) && (nbScan <= 256);

    if (ws_size >= need_base && packable) {
        char* p = (char*)d_ws;
        unsigned short* H      = (unsigned short*)p;           p += hB;
        unsigned short* Wt     = (unsigned short*)p;           p += wtB;
        int*            off    = (int*)p;                      p += offB;
        int*            deg    = (int*)p;                      p += degB;
        int*            ord    = (int*)p;                      p += ordB;
        int*            part   = (int*)p;                      p += parB;
        unsigned int*   sorted = (unsigned int*)p;             p += srtB;
        unsigned short* featb  = (ws_size >= need_full) ? (unsigned short*)p : nullptr;

        int wtTotal = R * D * D;
        int fcTotal = featb ? (N * D) / 8 : 0;
        int fcBlocks = (fcTotal + 255) / 256;
        int wtBlocks = (wtTotal + 255) / 256;
        int cntBlocks = (E + 255) / 256;

        hipMemsetAsync(deg, 0, (size_t)N * sizeof(int), stream);
        prep_kernel<<<fcBlocks + wtBlocks + cntBlocks, 256, 0, stream>>>(
            feat, featb, W, Wt, dst, deg, ord, fcTotal, wtTotal, E);

        // Phase 1: typed linear into H (no LDS, no barriers, high wave count)
        dim3 tg((N + 127) / 128, R);
        if (featb)
            transform6_kernel<<<tg, 256, 0, stream>>>(featb, Wt, H, N);
        else
            transform6f_kernel<<<tg, 256, 0, stream>>>(feat, Wt, H, N);

        // CSR build (by dst)
        k_blocksum<<<nbScan, 256, 0, stream>>>(deg, part, N);
        k_scanpart<<<1, 256, 0, stream>>>(part, nbScan);
        k_scanfinal<<<nbScan, 256, 0, stream>>>(deg, part, off, N, E);
        k_fill<<<cntBlocks, 256, 0, stream>>>(dst, et, src, off, ord, sorted, E);

        // Phase 2: gather-sum per node, fused with (1+eps)*feat
        k_gather2<<<(N + 3) / 4, 256, 0, stream>>>(H, sorted, off, feat, out, N);
    } else {
        int n4 = (N * D) / 4;
        init_kernel<<<(n4 + 255) / 256, 256, 0, stream>>>(feat, out, n4);
        edge_matvec_kernel<<<E, 128, 0, stream>>>(feat, W, et, src, dst, out, E);
    }
}

// Round 6
// 231.783 us; speedup vs baseline: 1.0077x; 1.0077x over previous
//
#include <hip/hip_runtime.h>
#include <hip/hip_bf16.h>
#include <stdint.h>

#define D 128

using bf16x8 = __attribute__((ext_vector_type(8))) short;
using f32x4  = __attribute__((ext_vector_type(4))) float;

__device__ __forceinline__ unsigned short f2bf(float f) {
    unsigned u = __float_as_uint(f);
    u = (u + 0x7fffu + ((u >> 16) & 1u)) >> 16;   // RNE
    return (unsigned short)u;
}
__device__ __forceinline__ float bf2f(unsigned short h) {
    return __uint_as_float(((unsigned)h) << 16);
}

// 8 fp32 -> 8 bf16 via packed HW cvt (RNE)
__device__ __forceinline__ bf16x8 cvt8(float4 a, float4 b) {
    union { bf16x8 v; __hip_bfloat162 h[4]; } u;
    u.h[0] = __float22bfloat162_rn(make_float2(a.x, a.y));
    u.h[1] = __float22bfloat162_rn(make_float2(a.z, a.w));
    u.h[2] = __float22bfloat162_rn(make_float2(b.x, b.y));
    u.h[3] = __float22bfloat162_rn(make_float2(b.z, b.w));
    return u.v;
}

// pack two f32x4 accumulators -> 8 bf16 (16 B)
__device__ __forceinline__ uint4 pack2(f32x4 x, f32x4 y) {
    union { uint4 u; __hip_bfloat162 h[4]; } o;
    o.h[0] = __float22bfloat162_rn(make_float2(x[0], x[1]));
    o.h[1] = __float22bfloat162_rn(make_float2(x[2], x[3]));
    o.h[2] = __float22bfloat162_rn(make_float2(y[0], y[1]));
    o.h[3] = __float22bfloat162_rn(make_float2(y[2], y[3]));
    return o.u;
}

// ---------- prep: feat->bf16 cast  +  Wt[r][c][k]=bf16(W[r][k][c])  +  degree count ----------
__global__ __launch_bounds__(256) void prep_kernel(
    const float* __restrict__ feat, unsigned short* __restrict__ featb,
    const float* __restrict__ W, unsigned short* __restrict__ Wt,
    const int* __restrict__ dst, int* __restrict__ deg, int* __restrict__ ord,
    int fcTotal /*chunks of 8*/, int wtTotal, int E)
{
    int fcBlocks = (fcTotal + 255) >> 8;
    int wtBlocks = (wtTotal + 255) >> 8;
    int b = blockIdx.x;
    if (b < fcBlocks) {
        int i = b * 256 + threadIdx.x;
        if (i < fcTotal && featb) {
            const float4* p = (const float4*)feat + (size_t)i * 2;
            float4 a = p[0], c = p[1];
            *(bf16x8*)(featb + (size_t)i * 8) = cvt8(a, c);
        }
    } else if (b < fcBlocks + wtBlocks) {
        int idx = (b - fcBlocks) * 256 + threadIdx.x;
        if (idx < wtTotal) {
            int r = idx >> 14;            // /(D*D)
            int rem = idx & 16383;
            int k = rem >> 7, c = rem & 127;
            Wt[(r << 14) + (c << 7) + k] = f2bf(W[idx]);
        }
    } else {
        int e = (b - fcBlocks - wtBlocks) * 256 + threadIdx.x;
        if (e < E) ord[e] = atomicAdd(&deg[dst[e]], 1);
    }
}

// ---------- Phase 1: H[r][n][perm(c)] = bf16( feat[n][:] @ W[r] ) ----------
// No LDS, no barriers; wave = 32 nodes x 1 rel; B-frags resident (32 VGPR),
// A-frags streamed from L2-hot Wt. H rows stored in a PERMUTED channel
// order so each lane stores one uint4 (16 B) per ct-pair and every store
// instruction covers full 64-B sectors (no partial-sector write amplification):
//   slot (j*4+q) holds channels {32j+4q..+3} U {32j+16+4q..+3}, j=ct>>1.
// Gather uses the matching per-lane channel map; downstream math is
// per-channel elementwise so the permutation is free.
__global__ __launch_bounds__(256) void transform7_kernel(
    const unsigned short* __restrict__ featb, const unsigned short* __restrict__ Wt,
    unsigned short* __restrict__ H, int N)
{
    const int rel  = blockIdx.y;
    const int tid  = threadIdx.x;
    const int wave = tid >> 6, lane = tid & 63;
    const int q    = lane >> 4, mlo = lane & 15;

    const int nb = blockIdx.x * 128 + wave * 32;   // wave's 32 nodes

    // B-frags: B[k = ks*32+q*8+j][n = mlo]
    bf16x8 bfr[2][4];
    #pragma unroll
    for (int g = 0; g < 2; ++g) {
        int node = nb + g * 16 + mlo;
        int ld = node < N ? node : N - 1;
        const unsigned short* fp = featb + (size_t)ld * D + q * 8;
        #pragma unroll
        for (int ks = 0; ks < 4; ++ks)
            bfr[g][ks] = *(const bf16x8*)(fp + ks * 32);
    }

    const unsigned short* wb = Wt + ((size_t)rel << 14) + (size_t)mlo * D + q * 8;
    const size_t Hb = (size_t)rel * N * D;
    const int n0 = nb + mlo, n1 = nb + 16 + mlo;
    unsigned short* h0 = H + Hb + (size_t)n0 * D + q * 8;
    unsigned short* h1 = H + Hb + (size_t)n1 * D + q * 8;

    #pragma unroll
    for (int j = 0; j < 4; ++j) {
        // A-frags for ct = 2j and 2j+1
        bf16x8 af0[4], af1[4];
        #pragma unroll
        for (int ks = 0; ks < 4; ++ks) {
            af0[ks] = *(const bf16x8*)(wb + (2 * j) * (16 * D) + ks * 32);
            af1[ks] = *(const bf16x8*)(wb + (2 * j + 1) * (16 * D) + ks * 32);
        }
        f32x4 a0 = {0.f,0.f,0.f,0.f}, a1 = {0.f,0.f,0.f,0.f};
        f32x4 b0 = {0.f,0.f,0.f,0.f}, b1 = {0.f,0.f,0.f,0.f};
        #pragma unroll
        for (int ks = 0; ks < 4; ++ks) {
            a0 = __builtin_amdgcn_mfma_f32_16x16x32_bf16(af0[ks], bfr[0][ks], a0, 0, 0, 0);
            a1 = __builtin_amdgcn_mfma_f32_16x16x32_bf16(af0[ks], bfr[1][ks], a1, 0, 0, 0);
            b0 = __builtin_amdgcn_mfma_f32_16x16x32_bf16(af1[ks], bfr[0][ks], b0, 0, 0, 0);
            b1 = __builtin_amdgcn_mfma_f32_16x16x32_bf16(af1[ks], bfr[1][ks], b1, 0, 0, 0);
        }
        // store 16 B per group: slot (j*4+q) -> short offset j*32 + q*8 (in h0/h1 base)
        if (n0 < N) *(uint4*)(h0 + j * 32) = pack2(a0, b0);
        if (n1 < N) *(uint4*)(h1 + j * 32) = pack2(a1, b1);
    }
}

// fp32-feat variant (used only when workspace can't hold featb) — same H layout
__global__ __launch_bounds__(256) void transform7f_kernel(
    const float* __restrict__ feat, const unsigned short* __restrict__ Wt,
    unsigned short* __restrict__ H, int N)
{
    const int rel  = blockIdx.y;
    const int tid  = threadIdx.x;
    const int wave = tid >> 6, lane = tid & 63;
    const int q    = lane >> 4, mlo = lane & 15;

    const int nb = blockIdx.x * 128 + wave * 32;

    bf16x8 bfr[2][4];
    #pragma unroll
    for (int g = 0; g < 2; ++g) {
        int node = nb + g * 16 + mlo;
        int ld = node < N ? node : N - 1;
        const float* fp = feat + (size_t)ld * D + q * 8;
        #pragma unroll
        for (int ks = 0; ks < 4; ++ks)
            bfr[g][ks] = cvt8(*(const float4*)(fp + ks * 32), *(const float4*)(fp + ks * 32 + 4));
    }

    const unsigned short* wb = Wt + ((size_t)rel << 14) + (size_t)mlo * D + q * 8;
    const size_t Hb = (size_t)rel * N * D;
    const int n0 = nb + mlo, n1 = nb + 16 + mlo;
    unsigned short* h0 = H + Hb + (size_t)n0 * D + q * 8;
    unsigned short* h1 = H + Hb + (size_t)n1 * D + q * 8;

    #pragma unroll
    for (int j = 0; j < 4; ++j) {
        bf16x8 af0[4], af1[4];
        #pragma unroll
        for (int ks = 0; ks < 4; ++ks) {
            af0[ks] = *(const bf16x8*)(wb + (2 * j) * (16 * D) + ks * 32);
            af1[ks] = *(const bf16x8*)(wb + (2 * j + 1) * (16 * D) + ks * 32);
        }
        f32x4 a0 = {0.f,0.f,0.f,0.f}, a1 = {0.f,0.f,0.f,0.f};
        f32x4 b0 = {0.f,0.f,0.f,0.f}, b1 = {0.f,0.f,0.f,0.f};
        #pragma unroll
        for (int ks = 0; ks < 4; ++ks) {
            a0 = __builtin_amdgcn_mfma_f32_16x16x32_bf16(af0[ks], bfr[0][ks], a0, 0, 0, 0);
            a1 = __builtin_amdgcn_mfma_f32_16x16x32_bf16(af0[ks], bfr[1][ks], a1, 0, 0, 0);
            b0 = __builtin_amdgcn_mfma_f32_16x16x32_bf16(af1[ks], bfr[0][ks], b0, 0, 0, 0);
            b1 = __builtin_amdgcn_mfma_f32_16x16x32_bf16(af1[ks], bfr[1][ks], b1, 0, 0, 0);
        }
        if (n0 < N) *(uint4*)(h0 + j * 32) = pack2(a0, b0);
        if (n1 < N) *(uint4*)(h1 + j * 32) = pack2(a1, b1);
    }
}

// ---------- CSR scan kernels ----------
__global__ __launch_bounds__(256) void k_blocksum(
    const int* __restrict__ deg, int* __restrict__ part, int N)
{
    int t = threadIdx.x, i = blockIdx.x * 256 + t;
    int v = (i < N) ? deg[i] : 0;
    #pragma unroll
    for (int o = 32; o > 0; o >>= 1) v += __shfl_down(v, o, 64);
    __shared__ int ws_[4];
    if ((t & 63) == 0) ws_[t >> 6] = v;
    __syncthreads();
    if (t == 0) part[blockIdx.x] = ws_[0] + ws_[1] + ws_[2] + ws_[3];
}

__global__ __launch_bounds__(256) void k_scanpart(int* part, int nb)
{
    __shared__ int s[256];
    int t = threadIdx.x;
    int v = (t < nb) ? part[t] : 0;
    s[t] = v;
    #pragma unroll
    for (int o = 1; o < 256; o <<= 1) {
        __syncthreads();
        int x = (t >= o) ? s[t - o] : 0;
        __syncthreads();
        s[t] += x;
    }
    if (t < nb) part[t] = s[t] - v;
}

__global__ __launch_bounds__(256) void k_scanfinal(
    const int* __restrict__ deg, const int* __restrict__ part,
    int* __restrict__ off, int N, int E)
{
    __shared__ int s[256];
    int t = threadIdx.x, i = blockIdx.x * 256 + t;
    int v = (i < N) ? deg[i] : 0;
    s[t] = v;
    #pragma unroll
    for (int o = 1; o < 256; o <<= 1) {
        __syncthreads();
        int x = (t >= o) ? s[t - o] : 0;
        __syncthreads();
        s[t] += x;
    }
    if (i < N) off[i] = part[blockIdx.x] + s[t] - v;
    if (i == 0) off[N] = E;
}

__global__ __launch_bounds__(256) void k_fill(
    const int* __restrict__ dst, const int* __restrict__ et,
    const int* __restrict__ src, const int* __restrict__ off,
    const int* __restrict__ ord, unsigned int* __restrict__ sorted, int E)
{
    int e = blockIdx.x * 256 + threadIdx.x;
    if (e >= E) return;
    sorted[off[dst[e]] + ord[e]] = ((unsigned)et[e] << 16) | (unsigned)src[e];
}

// ---------- Phase 2: gather. Wave = 8 contiguous nodes; off via one load+shfl;
// all 8 edge-packs preloaded; H loads 8-deep. Channel-pair map f matches
// transform7's permuted H-row layout. ----------
__global__ __launch_bounds__(256) void k_gather3(
    const unsigned short* __restrict__ H, const unsigned int* __restrict__ sorted,
    const int* __restrict__ off, const float* __restrict__ feat,
    float* __restrict__ out, int N)
{
    int wid = blockIdx.x * 4 + (threadIdx.x >> 6);
    int lane = threadIdx.x & 63;
    int base = wid * 8;
    if (base >= N) return;

    // permuted channel-pair index for this lane (matches transform7 slot layout)
    const int jj = lane >> 4, qq = (lane >> 2) & 3, pp = lane & 3;
    const int f = 16 * jj + 8 * (pp >> 1) + 2 * qq + (pp & 1);

    int oidx = base + lane; if (oidx > N) oidx = N;
    int offv = off[oidx];                    // lanes 0..8 carry off[base..base+8]

    unsigned ep[8]; int J0[8], DG[8];
    #pragma unroll
    for (int i = 0; i < 8; ++i) {
        int j0 = __shfl(offv, i), j1 = __shfl(offv, i + 1);
        if (base + i >= N) { j0 = 0; j1 = 0; }
        J0[i] = j0; DG[i] = j1 - j0;
        int d = DG[i];
        if (d > 0) ep[i] = sorted[j0 + (lane < d ? lane : d - 1)];
    }

    #pragma unroll
    for (int i = 0; i < 8; ++i) {
        int n = base + i;
        if (n >= N) break;
        float2 acc = ((const float2*)feat)[(size_t)n * 64 + f];
        int d = DG[i];
        int m = d < 64 ? d : 64;
        unsigned e = ep[i];
        int t = 0;
        for (; t + 8 <= m; t += 8) {
            unsigned a[8];
            #pragma unroll
            for (int u = 0; u < 8; ++u) {
                unsigned p = __shfl(e, t + u);
                a[u] = *(const unsigned*)(H + (((size_t)(p >> 16) * N + (p & 0xffffu)) << 7) + lane * 2);
            }
            #pragma unroll
            for (int u = 0; u < 8; ++u) {
                acc.x += bf2f((unsigned short)(a[u] & 0xffffu));
                acc.y += bf2f((unsigned short)(a[u] >> 16));
            }
        }
        for (; t < m; ++t) {
            unsigned p = __shfl(e, t);
            unsigned a0 = *(const unsigned*)(H + (((size_t)(p >> 16) * N + (p & 0xffffu)) << 7) + lane * 2);
            acc.x += bf2f((unsigned short)(a0 & 0xffffu));
            acc.y += bf2f((unsigned short)(a0 >> 16));
        }
        for (int t2 = J0[i] + 64; t2 < J0[i] + d; ++t2) {   // rare high-degree tail
            unsigned p = sorted[t2];
            unsigned a0 = *(const unsigned*)(H + (((size_t)(p >> 16) * N + (p & 0xffffu)) << 7) + lane * 2);
            acc.x += bf2f((unsigned short)(a0 & 0xffffu));
            acc.y += bf2f((unsigned short)(a0 >> 16));
        }
        ((float2*)out)[(size_t)n * 64 + f] = acc;
    }
}

// ---------- fallbacks ----------
__global__ __launch_bounds__(256) void init_kernel(
    const float* __restrict__ feat, float* __restrict__ out, int n4)
{
    int i = blockIdx.x * 256 + threadIdx.x;
    if (i < n4) ((float4*)out)[i] = ((const float4*)feat)[i];
}

__global__ __launch_bounds__(128) void edge_matvec_kernel(
    const float* __restrict__ feat, const float* __restrict__ W,
    const int* __restrict__ et, const int* __restrict__ src,
    const int* __restrict__ dst, float* __restrict__ out, int E)
{
    __shared__ float xs[D];
    int e = blockIdx.x;
    int c = threadIdx.x;
    int s = src[e], r = et[e], d = dst[e];
    xs[c] = feat[(size_t)s * D + c];
    __syncthreads();
    const float* Wr = W + (size_t)r * D * D;
    float acc = 0.f;
    #pragma unroll 8
    for (int k = 0; k < D; ++k) acc += xs[k] * Wr[(size_t)k * D + c];
    atomicAdd(out + (size_t)d * D + c, acc);
}

static inline size_t al256(size_t x) { return (x + 255) & ~(size_t)255; }

extern "C" void kernel_launch(void* const* d_in, const int* in_sizes, int n_in,
                              void* d_out, int out_size, void* d_ws, size_t ws_size,
                              hipStream_t stream) {
    const float* feat = (const float*)d_in[0];
    const float* W    = (const float*)d_in[1];
    const int*   et   = (const int*)d_in[2];
    const int*   src  = (const int*)d_in[3];
    const int*   dst  = (const int*)d_in[4];
    float* out = (float*)d_out;

    const int N = in_sizes[0] / D;
    const int R = in_sizes[1] / (D * D);
    const int E = in_sizes[2];

    size_t hB   = al256((size_t)R * N * D * sizeof(unsigned short));
    size_t wtB  = al256((size_t)R * D * D * sizeof(unsigned short));
    size_t offB = al256((size_t)(N + 1) * sizeof(int));
    size_t degB = al256((size_t)N * sizeof(int));
    size_t ordB = al256((size_t)E * sizeof(int));
    size_t parB = al256(1024 * sizeof(int));
    size_t srtB = al256((size_t)E * sizeof(unsigned int));
    size_t fbB  = al256((size_t)N * D * sizeof(unsigned short));
    size_t need_base = hB + wtB + offB + degB + ordB + parB + srtB;
    size_t need_full = need_base + fbB;

    const int nbScan = (N + 255) / 256;
    const bool packable = (N <= 65536) && (R <= 65536) && (nbScan <= 256);

    if (ws_size >= need_base && packable) {
        char* p = (char*)d_ws;
        unsigned short* H      = (unsigned short*)p;           p += hB;
        unsigned short* Wt     = (unsigned short*)p;           p += wtB;
        int*            off    = (int*)p;                      p += offB;
        int*            deg    = (int*)p;                      p += degB;
        int*            ord    = (int*)p;                      p += ordB;
        int*            part   = (int*)p;                      p += parB;
        unsigned int*   sorted = (unsigned int*)p;             p += srtB;
        unsigned short* featb  = (ws_size >= need_full) ? (unsigned short*)p : nullptr;

        int wtTotal = R * D * D;
        int fcTotal = featb ? (N * D) / 8 : 0;
        int fcBlocks = (fcTotal + 255) / 256;
        int wtBlocks = (wtTotal + 255) / 256;
        int cntBlocks = (E + 255) / 256;

        hipMemsetAsync(deg, 0, (size_t)N * sizeof(int), stream);
        prep_kernel<<<fcBlocks + wtBlocks + cntBlocks, 256, 0, stream>>>(
            feat, featb, W, Wt, dst, deg, ord, fcTotal, wtTotal, E);

        // Phase 1: typed linear into H (permuted row layout, sector-aligned stores)
        dim3 tg((N + 127) / 128, R);
        if (featb)
            transform7_kernel<<<tg, 256, 0, stream>>>(featb, Wt, H, N);
        else
            transform7f_kernel<<<tg, 256, 0, stream>>>(feat, Wt, H, N);

        // CSR build (by dst)
        k_blocksum<<<nbScan, 256, 0, stream>>>(deg, part, N);
        k_scanpart<<<1, 256, 0, stream>>>(part, nbScan);
        k_scanfinal<<<nbScan, 256, 0, stream>>>(deg, part, off, N, E);
        k_fill<<<cntBlocks, 256, 0, stream>>>(dst, et, src, off, ord, sorted, E);

        // Phase 2: gather-sum, 8 nodes/wave, fused with (1+eps)*feat
        int nw = (N + 7) / 8;
        k_gather3<<<(nw + 3) / 4, 256, 0, stream>>>(H, sorted, off, feat, out, N);
    } else {
        int n4 = (N * D) / 4;
        init_kernel<<<(n4 + 255) / 256, 256, 0, stream>>>(feat, out, n4);
        edge_matvec_kernel<<<E, 128, 0, stream>>>(feat, W, et, src, dst, out, E);
    }
}

// Round 7
// 196.866 us; speedup vs baseline: 1.1865x; 1.1774x over previous
//
#include <hip/hip_runtime.h>
#include <hip/hip_bf16.h>
#include <stdint.h>

#define D 128

using bf16x8 = __attribute__((ext_vector_type(8))) short;
using f32x4  = __attribute__((ext_vector_type(4))) float;

__device__ __forceinline__ unsigned short f2bf(float f) {
    unsigned u = __float_as_uint(f);
    u = (u + 0x7fffu + ((u >> 16) & 1u)) >> 16;   // RNE
    return (unsigned short)u;
}
__device__ __forceinline__ float bf2f(unsigned short h) {
    return __uint_as_float(((unsigned)h) << 16);
}

// 8 fp32 -> 8 bf16 via packed HW cvt (RNE)
__device__ __forceinline__ bf16x8 cvt8(float4 a, float4 b) {
    union { bf16x8 v; __hip_bfloat162 h[4]; } u;
    u.h[0] = __float22bfloat162_rn(make_float2(a.x, a.y));
    u.h[1] = __float22bfloat162_rn(make_float2(a.z, a.w));
    u.h[2] = __float22bfloat162_rn(make_float2(b.x, b.y));
    u.h[3] = __float22bfloat162_rn(make_float2(b.z, b.w));
    return u.v;
}

// pack two f32x4 accumulators -> 8 bf16 (16 B)
__device__ __forceinline__ uint4 pack2(f32x4 x, f32x4 y) {
    union { uint4 u; __hip_bfloat162 h[4]; } o;
    o.h[0] = __float22bfloat162_rn(make_float2(x[0], x[1]));
    o.h[1] = __float22bfloat162_rn(make_float2(x[2], x[3]));
    o.h[2] = __float22bfloat162_rn(make_float2(y[0], y[1]));
    o.h[3] = __float22bfloat162_rn(make_float2(y[2], y[3]));
    return o.u;
}

// ---------- prep: feat->bf16 cast  +  Wt[r][c][k]=bf16(W[r][k][c])  +  degree count ----------
__global__ __launch_bounds__(256) void prep_kernel(
    const float* __restrict__ feat, unsigned short* __restrict__ featb,
    const float* __restrict__ W, unsigned short* __restrict__ Wt,
    const int* __restrict__ dst, int* __restrict__ deg, int* __restrict__ ord,
    int fcTotal /*chunks of 8*/, int wtTotal, int E)
{
    int fcBlocks = (fcTotal + 255) >> 8;
    int wtBlocks = (wtTotal + 255) >> 8;
    int b = blockIdx.x;
    if (b < fcBlocks) {
        int i = b * 256 + threadIdx.x;
        if (i < fcTotal && featb) {
            const float4* p = (const float4*)feat + (size_t)i * 2;
            float4 a = p[0], c = p[1];
            *(bf16x8*)(featb + (size_t)i * 8) = cvt8(a, c);
        }
    } else if (b < fcBlocks + wtBlocks) {
        int idx = (b - fcBlocks) * 256 + threadIdx.x;
        if (idx < wtTotal) {
            int r = idx >> 14;            // /(D*D)
            int rem = idx & 16383;
            int k = rem >> 7, c = rem & 127;
            Wt[(r << 14) + (c << 7) + k] = f2bf(W[idx]);
        }
    } else {
        int e = (b - fcBlocks - wtBlocks) * 256 + threadIdx.x;
        if (e < E) ord[e] = atomicAdd(&deg[dst[e]], 1);
    }
}

// ---------- Phase 1: H[r][n][perm(c)] = bf16( feat[n][:] @ W[r] ) ----------
// rel = blockIdx.y. Wt[rel] staged ONCE per block into XOR-swizzled LDS
// (ONE barrier total); A-frags via conflict-free ds_read_b128; wave = 32
// nodes (2 groups of 16), B-frags from featb; stores use the permuted
// sector-aligned uint4 layout (slot j*4+q holds channels {32j+4q..+3} U
// {32j+16+4q..+3}) so every store covers full 64-B sectors.
__global__ __launch_bounds__(256) void transform8_kernel(
    const unsigned short* __restrict__ featb, const unsigned short* __restrict__ Wt,
    unsigned short* __restrict__ H, int N)
{
    __shared__ __align__(16) unsigned short sW[128 * 128];   // 32 KB
    const int rel  = blockIdx.y;
    const int tid  = threadIdx.x;
    const int wave = tid >> 6, lane = tid & 63;
    const int q    = lane >> 4, mlo = lane & 15;

    // stage Wt[rel] -> LDS, swizzled: row c, chunk ch (16 B) at (ch ^ (c&15))
    {
        const ulonglong2* wsrc = (const ulonglong2*)(Wt + ((size_t)rel << 14));
        #pragma unroll
        for (int i = 0; i < 8; ++i) {
            int idx = tid + 256 * i;           // 0..2047
            int row = idx >> 4, ch = idx & 15;
            ulonglong2 v = wsrc[idx];
            *(ulonglong2*)&sW[row * 128 + ((ch ^ (row & 15)) * 8)] = v;
        }
    }

    // B-frags: 2 groups of 16 nodes; B[k=ks*32+q*8+j][n=mlo]
    const int nb = blockIdx.x * 128 + wave * 32;
    bf16x8 bfr[2][4];
    int nodeg[2];
    #pragma unroll
    for (int g = 0; g < 2; ++g) {
        int node = nb + g * 16 + mlo;
        nodeg[g] = node;
        int ld = node < N ? node : N - 1;
        const unsigned short* fp = featb + (size_t)ld * D + q * 8;
        #pragma unroll
        for (int ks = 0; ks < 4; ++ks)
            bfr[g][ks] = *(const bf16x8*)(fp + ks * 32);
    }
    __syncthreads();

    const size_t Hb = (size_t)rel * N * D;
    unsigned short* hp0 = H + Hb + (size_t)nodeg[0] * D + q * 8;
    unsigned short* hp1 = H + Hb + (size_t)nodeg[1] * D + q * 8;

    #pragma unroll
    for (int j = 0; j < 4; ++j) {
        // A-frags for ct = 2j, 2j+1 from LDS (conflict-free swizzle)
        bf16x8 af0[4], af1[4];
        const int row0 = (2 * j) * 16 + mlo, row1 = row0 + 16;
        #pragma unroll
        for (int ks = 0; ks < 4; ++ks) {
            af0[ks] = *(const bf16x8*)&sW[row0 * 128 + (((ks * 4 + q) ^ mlo) * 8)];
            af1[ks] = *(const bf16x8*)&sW[row1 * 128 + (((ks * 4 + q) ^ mlo) * 8)];
        }
        #pragma unroll
        for (int g = 0; g < 2; ++g) {
            f32x4 a = {0.f,0.f,0.f,0.f}, b = {0.f,0.f,0.f,0.f};
            #pragma unroll
            for (int ks = 0; ks < 4; ++ks) {
                a = __builtin_amdgcn_mfma_f32_16x16x32_bf16(af0[ks], bfr[g][ks], a, 0, 0, 0);
                b = __builtin_amdgcn_mfma_f32_16x16x32_bf16(af1[ks], bfr[g][ks], b, 0, 0, 0);
            }
            if (nodeg[g] < N)
                *(uint4*)((g ? hp1 : hp0) + j * 32) = pack2(a, b);
        }
    }
}

// fp32-feat variant (used only when workspace can't hold featb) — same layout
__global__ __launch_bounds__(256) void transform8f_kernel(
    const float* __restrict__ feat, const unsigned short* __restrict__ Wt,
    unsigned short* __restrict__ H, int N)
{
    __shared__ __align__(16) unsigned short sW[128 * 128];
    const int rel  = blockIdx.y;
    const int tid  = threadIdx.x;
    const int wave = tid >> 6, lane = tid & 63;
    const int q    = lane >> 4, mlo = lane & 15;

    {
        const ulonglong2* wsrc = (const ulonglong2*)(Wt + ((size_t)rel << 14));
        #pragma unroll
        for (int i = 0; i < 8; ++i) {
            int idx = tid + 256 * i;
            int row = idx >> 4, ch = idx & 15;
            ulonglong2 v = wsrc[idx];
            *(ulonglong2*)&sW[row * 128 + ((ch ^ (row & 15)) * 8)] = v;
        }
    }

    const int nb = blockIdx.x * 128 + wave * 32;
    bf16x8 bfr[2][4];
    int nodeg[2];
    #pragma unroll
    for (int g = 0; g < 2; ++g) {
        int node = nb + g * 16 + mlo;
        nodeg[g] = node;
        int ld = node < N ? node : N - 1;
        const float* fp = feat + (size_t)ld * D + q * 8;
        #pragma unroll
        for (int ks = 0; ks < 4; ++ks)
            bfr[g][ks] = cvt8(*(const float4*)(fp + ks * 32), *(const float4*)(fp + ks * 32 + 4));
    }
    __syncthreads();

    const size_t Hb = (size_t)rel * N * D;
    unsigned short* hp0 = H + Hb + (size_t)nodeg[0] * D + q * 8;
    unsigned short* hp1 = H + Hb + (size_t)nodeg[1] * D + q * 8;

    #pragma unroll
    for (int j = 0; j < 4; ++j) {
        bf16x8 af0[4], af1[4];
        const int row0 = (2 * j) * 16 + mlo, row1 = row0 + 16;
        #pragma unroll
        for (int ks = 0; ks < 4; ++ks) {
            af0[ks] = *(const bf16x8*)&sW[row0 * 128 + (((ks * 4 + q) ^ mlo) * 8)];
            af1[ks] = *(const bf16x8*)&sW[row1 * 128 + (((ks * 4 + q) ^ mlo) * 8)];
        }
        #pragma unroll
        for (int g = 0; g < 2; ++g) {
            f32x4 a = {0.f,0.f,0.f,0.f}, b = {0.f,0.f,0.f,0.f};
            #pragma unroll
            for (int ks = 0; ks < 4; ++ks) {
                a = __builtin_amdgcn_mfma_f32_16x16x32_bf16(af0[ks], bfr[g][ks], a, 0, 0, 0);
                b = __builtin_amdgcn_mfma_f32_16x16x32_bf16(af1[ks], bfr[g][ks], b, 0, 0, 0);
            }
            if (nodeg[g] < N)
                *(uint4*)((g ? hp1 : hp0) + j * 32) = pack2(a, b);
        }
    }
}

// ---------- CSR scan kernels ----------
__global__ __launch_bounds__(256) void k_blocksum(
    const int* __restrict__ deg, int* __restrict__ part, int N)
{
    int t = threadIdx.x, i = blockIdx.x * 256 + t;
    int v = (i < N) ? deg[i] : 0;
    #pragma unroll
    for (int o = 32; o > 0; o >>= 1) v += __shfl_down(v, o, 64);
    __shared__ int ws_[4];
    if ((t & 63) == 0) ws_[t >> 6] = v;
    __syncthreads();
    if (t == 0) part[blockIdx.x] = ws_[0] + ws_[1] + ws_[2] + ws_[3];
}

__global__ __launch_bounds__(256) void k_scanpart(int* part, int nb)
{
    __shared__ int s[256];
    int t = threadIdx.x;
    int v = (t < nb) ? part[t] : 0;
    s[t] = v;
    #pragma unroll
    for (int o = 1; o < 256; o <<= 1) {
        __syncthreads();
        int x = (t >= o) ? s[t - o] : 0;
        __syncthreads();
        s[t] += x;
    }
    if (t < nb) part[t] = s[t] - v;
}

__global__ __launch_bounds__(256) void k_scanfinal(
    const int* __restrict__ deg, const int* __restrict__ part,
    int* __restrict__ off, int N, int E)
{
    __shared__ int s[256];
    int t = threadIdx.x, i = blockIdx.x * 256 + t;
    int v = (i < N) ? deg[i] : 0;
    s[t] = v;
    #pragma unroll
    for (int o = 1; o < 256; o <<= 1) {
        __syncthreads();
        int x = (t >= o) ? s[t - o] : 0;
        __syncthreads();
        s[t] += x;
    }
    if (i < N) off[i] = part[blockIdx.x] + s[t] - v;
    if (i == 0) off[N] = E;
}

// fill: sorted[] holds precomputed H BYTE offsets ((et*N+src)*256)
__global__ __launch_bounds__(256) void k_fill(
    const int* __restrict__ dst, const int* __restrict__ et,
    const int* __restrict__ src, const int* __restrict__ off,
    const int* __restrict__ ord, unsigned int* __restrict__ sorted, int E, int N)
{
    int e = blockIdx.x * 256 + threadIdx.x;
    if (e >= E) return;
    unsigned key = ((unsigned)et[e] * (unsigned)N + (unsigned)src[e]) << 8;
    sorted[off[dst[e]] + ord[e]] = key;
}

// ---------- Phase 2: gather. 1 node per wave; 16-deep predicated pipeline;
// sorted[] holds H byte-offsets. Channel map f matches transform8 layout. ----------
__global__ __launch_bounds__(256) void k_gather4(
    const char* __restrict__ Hc, const unsigned int* __restrict__ sorted,
    const int* __restrict__ off, const float* __restrict__ feat,
    float* __restrict__ out, int N)
{
    int n = blockIdx.x * 4 + (threadIdx.x >> 6);
    if (n >= N) return;
    int lane = threadIdx.x & 63;

    // permuted channel-pair index (matches transform8 slot layout)
    const int jj = lane >> 4, qq = (lane >> 2) & 3, pp = lane & 3;
    const int f = 16 * jj + 8 * (pp >> 1) + 2 * qq + (pp & 1);

    float2 acc = ((const float2*)feat)[(size_t)n * 64 + f];   // (1+eps)*h

    int j0 = __builtin_amdgcn_readfirstlane(off[n]);
    int j1 = __builtin_amdgcn_readfirstlane(off[n + 1]);
    int deg = j1 - j0;
    if (deg > 0) {
        unsigned ep = sorted[j0 + (lane < deg ? lane : deg - 1)];
        int capped = deg < 64 ? deg : 64;
        for (int done = 0; done < capped; done += 16) {
            unsigned a[16];
            #pragma unroll
            for (int u = 0; u < 16; ++u) {
                int idx = done + u; idx = idx < capped ? idx : capped - 1;
                unsigned p = __shfl(ep, idx);
                a[u] = *(const unsigned*)(Hc + p + lane * 4);
            }
            #pragma unroll
            for (int u = 0; u < 16; ++u) {
                bool v = (done + u) < capped;
                acc.x += v ? bf2f((unsigned short)(a[u] & 0xffffu)) : 0.f;
                acc.y += v ? bf2f((unsigned short)(a[u] >> 16)) : 0.f;
            }
        }
        for (int j = j0 + 64; j < j1; ++j) {   // rare high-degree tail
            unsigned p = sorted[j];
            unsigned a0 = *(const unsigned*)(Hc + p + lane * 4);
            acc.x += bf2f((unsigned short)(a0 & 0xffffu));
            acc.y += bf2f((unsigned short)(a0 >> 16));
        }
    }
    ((float2*)out)[(size_t)n * 64 + f] = acc;
}

// ---------- fallbacks ----------
__global__ __launch_bounds__(256) void init_kernel(
    const float* __restrict__ feat, float* __restrict__ out, int n4)
{
    int i = blockIdx.x * 256 + threadIdx.x;
    if (i < n4) ((float4*)out)[i] = ((const float4*)feat)[i];
}

__global__ __launch_bounds__(128) void edge_matvec_kernel(
    const float* __restrict__ feat, const float* __restrict__ W,
    const int* __restrict__ et, const int* __restrict__ src,
    const int* __restrict__ dst, float* __restrict__ out, int E)
{
    __shared__ float xs[D];
    int e = blockIdx.x;
    int c = threadIdx.x;
    int s = src[e], r = et[e], d = dst[e];
    xs[c] = feat[(size_t)s * D + c];
    __syncthreads();
    const float* Wr = W + (size_t)r * D * D;
    float acc = 0.f;
    #pragma unroll 8
    for (int k = 0; k < D; ++k) acc += xs[k] * Wr[(size_t)k * D + c];
    atomicAdd(out + (size_t)d * D + c, acc);
}

static inline size_t al256(size_t x) { return (x + 255) & ~(size_t)255; }

extern "C" void kernel_launch(void* const* d_in, const int* in_sizes, int n_in,
                              void* d_out, int out_size, void* d_ws, size_t ws_size,
                              hipStream_t stream) {
    const float* feat = (const float*)d_in[0];
    const float* W    = (const float*)d_in[1];
    const int*   et   = (const int*)d_in[2];
    const int*   src  = (const int*)d_in[3];
    const int*   dst  = (const int*)d_in[4];
    float* out = (float*)d_out;

    const int N = in_sizes[0] / D;
    const int R = in_sizes[1] / (D * D);
    const int E = in_sizes[2];

    size_t hB   = al256((size_t)R * N * D * sizeof(unsigned short));
    size_t wtB  = al256((size_t)R * D * D * sizeof(unsigned short));
    size_t offB = al256((size_t)(N + 1) * sizeof(int));
    size_t degB = al256((size_t)N * sizeof(int));
    size_t ordB = al256((size_t)E * sizeof(int));
    size_t parB = al256(1024 * sizeof(int));
    size_t srtB = al256((size_t)E * sizeof(unsigned int));
    size_t fbB  = al256((size_t)N * D * sizeof(unsigned short));
    size_t need_base = hB + wtB + offB + degB + ordB + parB + srtB;
    size_t need_full = need_base + fbB;

    const int nbScan = (N + 255) / 256;
    const bool packable = (nbScan <= 256) &&
                          ((size_t)R * (size_t)N * 256ull <= 0xFFFFFFFFull);

    if (ws_size >= need_base && packable) {
        char* p = (char*)d_ws;
        unsigned short* H      = (unsigned short*)p;           p += hB;
        unsigned short* Wt     = (unsigned short*)p;           p += wtB;
        int*            off    = (int*)p;                      p += offB;
        int*            deg    = (int*)p;                      p += degB;
        int*            ord    = (int*)p;                      p += ordB;
        int*            part   = (int*)p;                      p += parB;
        unsigned int*   sorted = (unsigned int*)p;             p += srtB;
        unsigned short* featb  = (ws_size >= need_full) ? (unsigned short*)p : nullptr;

        int wtTotal = R * D * D;
        int fcTotal = featb ? (N * D) / 8 : 0;
        int fcBlocks = (fcTotal + 255) / 256;
        int wtBlocks = (wtTotal + 255) / 256;
        int cntBlocks = (E + 255) / 256;

        hipMemsetAsync(deg, 0, (size_t)N * sizeof(int), stream);
        prep_kernel<<<fcBlocks + wtBlocks + cntBlocks, 256, 0, stream>>>(
            feat, featb, W, Wt, dst, deg, ord, fcTotal, wtTotal, E);

        // Phase 1: typed linear into H (LDS-resident W, one barrier, sector stores)
        dim3 tg((N + 127) / 128, R);
        if (featb)
            transform8_kernel<<<tg, 256, 0, stream>>>(featb, Wt, H, N);
        else
            transform8f_kernel<<<tg, 256, 0, stream>>>(feat, Wt, H, N);

        // CSR build (by dst)
        k_blocksum<<<nbScan, 256, 0, stream>>>(deg, part, N);
        k_scanpart<<<1, 256, 0, stream>>>(part, nbScan);
        k_scanfinal<<<nbScan, 256, 0, stream>>>(deg, part, off, N, E);
        k_fill<<<cntBlocks, 256, 0, stream>>>(dst, et, src, off, ord, sorted, E, N);

        // Phase 2: gather-sum, 1 node/wave, 16-deep pipeline
        k_gather4<<<(N + 3) / 4, 256, 0, stream>>>((const char*)H, sorted, off, feat, out, N);
    } else {
        int n4 = (N * D) / 4;
        init_kernel<<<(n4 + 255) / 256, 256, 0, stream>>>(feat, out, n4);
        edge_matvec_kernel<<<E, 128, 0, stream>>>(feat, W, et, src, dst, out, E);
    }
}